// Round 9
// baseline (372.904 us; speedup 1.0000x reference)
//
#include <hip/hip_runtime.h>

// WindowAttention: B=256 windows, N=256 tokens, C=384, 12 heads, d=32.
// Pipeline: K0 cast weights->bf16 | K1 transpose-cast x -> xt (B*N,C) bf16
//           K2 per-(b,h): qkv MFMA GEMM + l2norm + MFMA attention -> xa bf16
//           K3 proj MFMA GEMM (96-ch tiles) + output transpose -> (B,C,N) f32
// MFMA 16x16x32 bf16 layouts (verified m89/m91/m120):
//   A: A[m][k] m=lane&15, k=(lane>>4)*8+j ; B: B[k][n] n=lane&15, k=(lane>>4)*8+j
//   D: col=lane&15, row=(lane>>4)*4+r
// Softmax: logits in [-0.178,0.178] -> no max-subtract; clip(1e-6,1) no-op.
// SCALE/ln2 folded into qhat so p = exp2(s).
// R9 changes vs R8 (368us; K2=150 at 1 blk/CU [77KB LDS x2 > ~147KB usable];
// K3~150 with 16-seg xa gathers at only 3 MFMA/gather):
//  (a) K2 K-SPLIT weight staging: stage W[96][192] halves (38.4KB), kc 0-5, barrier,
//      restage, kc 6-11. LDS max 54.1KB -> 2 blocks/CU (44% occ target): one block's
//      phase-C VALU overlaps the other's phase-A MFMA (separate pipes).
//  (b) K3 96-ch tiles: acc[6][4], 6 MFMA/gather (2x R8), xa re-read 4x not 8x;
//      same K-split weight staging; launch_bounds(256,2) -- no spill possible.

#define DIM 384
#define NT 256
#define NH 12
#define HD 32
#define QSCALE (0.17677669529663687f * 1.4426950408889634f)  // SCALE/ln2

typedef __bf16 bf16;
typedef __bf16 bf16x4 __attribute__((ext_vector_type(4)));
typedef __bf16 bf16x8 __attribute__((ext_vector_type(8)));
typedef float f32x4 __attribute__((ext_vector_type(4)));
typedef int i32x2 __attribute__((ext_vector_type(2)));
typedef int i32x4 __attribute__((ext_vector_type(4)));

#define MFMA16(a, b, c) __builtin_amdgcn_mfma_f32_16x16x32_bf16(a, b, c, 0, 0, 0)

// zero-VALU: combine two bf16x4 (2 VGPRs each) into a bf16x8 by register renaming
static __device__ __forceinline__ bf16x8 pack2(bf16x4 lo, bf16x4 hi) {
    i32x2 a = __builtin_bit_cast(i32x2, lo);
    i32x2 c = __builtin_bit_cast(i32x2, hi);
    i32x4 v = {a[0], a[1], c[0], c[1]};
    return __builtin_bit_cast(bf16x8, v);
}

// ---------------- K0: cast weights to bf16 ----------------
__global__ void k_cast_w(const float* __restrict__ qkv_w, const float* __restrict__ proj_w,
                         bf16* __restrict__ wq, bf16* __restrict__ wp) {
    int i = blockIdx.x * 256 + threadIdx.x;
    if (i < 3 * DIM * DIM) wq[i] = (bf16)qkv_w[i];
    if (i < DIM * DIM)     wp[i] = (bf16)proj_w[i];
}

// ---------------- K1: x (B,C,N) f32 -> xt (B*N, C) bf16 ----------------
__global__ void k_transpose_cast(const float* __restrict__ x, bf16* __restrict__ xt) {
    __shared__ float tile[32][33];
    int b = blockIdx.z;
    int c0 = blockIdx.y * 32;
    int n0 = blockIdx.x * 32;
    int tx = threadIdx.x, ty = threadIdx.y;
    const float* xp = x + (size_t)b * DIM * NT;
#pragma unroll
    for (int i = 0; i < 4; ++i) {
        int c = c0 + ty + i * 8;
        tile[ty + i * 8][tx] = xp[(size_t)c * NT + n0 + tx];
    }
    __syncthreads();
    bf16* op = xt + (size_t)b * NT * DIM;
#pragma unroll
    for (int i = 0; i < 4; ++i) {
        int n = n0 + ty + i * 8;
        op[(size_t)n * DIM + c0 + tx] = (bf16)tile[tx][ty + i * 8];
    }
}

// ---------------- K2: fused qkv GEMM + l2norm + attention, one block per (b,h) ----------------
__launch_bounds__(512, 3)
__global__ void k_qkv_attn(const bf16* __restrict__ xt, const bf16* __restrict__ wq,
                           const float* __restrict__ qkv_b, bf16* __restrict__ attn_out) {
    // LDS union: phase A = half weight tile 96x200 bf16 (38,400B, restaged once);
    //            phase C = kn 20,480 + vT 16,896 + qn 16,384 = 53,760B (overlaid).
    __shared__ __align__(16) char smem[53760];
    bf16 (*wsm)[200] = (bf16(*)[200])smem;              // 96 rows x 192 kdims (pad 200)
    bf16 (*kn)[40]   = (bf16(*)[40])smem;               // normalized k (pad 40)
    bf16 (*vT)[264]  = (bf16(*)[264])(smem + 20480);    // v^T [d][token] (pad 264)
    bf16 (*qn)[32]   = (bf16(*)[32])(smem + 37376);     // normalized q*QSCALE
    __shared__ float bias_s[96];

    // XCD-pinned decode: all 12 head-blocks of a batch share one XCD/L2.
    const int n_ = blockIdx.x;            // grid = 3072 (bijective remap of (h,b))
    const int xcd = n_ & 7;
    const int ww = n_ >> 3;               // 0..383
    const int b = xcd * 32 + ww / 12;
    const int h = ww % 12;

    const int tid = threadIdx.x;
    const int lane = tid & 63, w = tid >> 6;   // w = 0..7
    const int l15 = lane & 15, quad = lane >> 4;

    if (tid < 96) {
        int which = tid >> 5;
        bias_s[tid] = qkv_b[which * DIM + h * HD + (tid & 31)];
    }
    // ---- stage half hk of this head's 96x384 weight tile (96x192 = 2304 chunks) ----
    auto stage_w = [&](int hk) {
#pragma unroll
        for (int i = 0; i < 5; ++i) {
            int c = tid + i * 512;
            if (c < 2304) {
                int row = c / 24, ch = c % 24;
                int grow = (row >> 5) * DIM + h * HD + (row & 31);   // q/k/v row in wq
                *(bf16x8*)&wsm[row][ch * 8] =
                    *(const bf16x8*)(wq + (size_t)grow * DIM + hk * 192 + ch * 8);
            }
        }
    };
    stage_w(0);
    __syncthreads();

    // ---- Phase A: qkv GEMM, wave w owns tokens [w*32, w*32+32), acc[6][2]=48 regs.
    // A-frags from LDS; x B-frags global with one-ahead dbuf. kc split 0-5 / 6-11.
    f32x4 acc[6][2];
#pragma unroll
    for (int jt = 0; jt < 6; ++jt)
#pragma unroll
        for (int tt = 0; tt < 2; ++tt) acc[jt][tt] = (f32x4){0.f, 0.f, 0.f, 0.f};

    const bf16* xrow[2];
#pragma unroll
    for (int tt = 0; tt < 2; ++tt) {
        int tok = w * 32 + tt * 16 + l15;
        xrow[tt] = xt + (size_t)(b * NT + tok) * DIM + quad * 8;
    }

    bf16x8 bx[2][2];
#pragma unroll
    for (int tt = 0; tt < 2; ++tt) bx[0][tt] = *(const bf16x8*)(xrow[tt]);

#pragma unroll 1
    for (int hk = 0; hk < 2; ++hk) {
        if (hk) {
            __syncthreads();   // all waves done reading half 0
            stage_w(1);
            __syncthreads();
        }
#pragma unroll
        for (int kc6 = 0; kc6 < 6; ++kc6) {
            const int kc = hk * 6 + kc6;
            const int cur = kc & 1, nxt = cur ^ 1;
            if (kc < 11) {
                int k0 = (kc + 1) * 32;
#pragma unroll
                for (int tt = 0; tt < 2; ++tt) bx[nxt][tt] = *(const bf16x8*)(xrow[tt] + k0);
            }
            bf16x8 aw[6];
#pragma unroll
            for (int jt = 0; jt < 6; ++jt)
                aw[jt] = *(const bf16x8*)&wsm[jt * 16 + l15][kc6 * 32 + quad * 8];
#pragma unroll
            for (int jt = 0; jt < 6; ++jt)
#pragma unroll
                for (int tt = 0; tt < 2; ++tt)
                    acc[jt][tt] = MFMA16(aw[jt], bx[cur][tt], acc[jt][tt]);
        }
    }
    __syncthreads();   // weights dead; epilogue overlays kn/qn/vT

    // ---- epilogue: +bias, l2-normalize q,k; q->qn, k->kn (b64 stores), v->vT.
#pragma unroll
    for (int tt = 0; tt < 2; ++tt) {
        int tok = w * 32 + tt * 16 + l15;  // = D col for this frag
        float sq = 0.f, sk = 0.f;
#pragma unroll
        for (int jt = 0; jt < 6; ++jt)
#pragma unroll
            for (int r = 0; r < 4; ++r) {
                int j = jt * 16 + quad * 4 + r;  // D row
                float t = acc[jt][tt][r] + bias_s[j];
                acc[jt][tt][r] = t;
                if (jt < 2) sq += t * t;
                else if (jt < 4) sk += t * t;
            }
        sq += __shfl_xor(sq, 16); sq += __shfl_xor(sq, 32);
        sk += __shfl_xor(sk, 16); sk += __shfl_xor(sk, 32);
        float iq = QSCALE / fmaxf(sqrtf(sq), 1e-12f);
        float ik = 1.f / fmaxf(sqrtf(sk), 1e-12f);

        bf16x4 q0v, q1v, k0v, k1v;
#pragma unroll
        for (int r = 0; r < 4; ++r) {
            q0v[r] = (bf16)(acc[0][tt][r] * iq);
            q1v[r] = (bf16)(acc[1][tt][r] * iq);
            k0v[r] = (bf16)(acc[2][tt][r] * ik);
            k1v[r] = (bf16)(acc[3][tt][r] * ik);
        }
        *(bf16x4*)&qn[tok][quad * 4]      = q0v;
        *(bf16x4*)&qn[tok][16 + quad * 4] = q1v;
        *(bf16x4*)&kn[tok][quad * 4]      = k0v;
        *(bf16x4*)&kn[tok][16 + quad * 4] = k1v;
#pragma unroll
        for (int r = 0; r < 4; ++r) {
            vT[quad * 4 + r][tok]      = (bf16)acc[4][tt][r];
            vT[16 + quad * 4 + r][tok] = (bf16)acc[5][tt][r];
        }
    }
    __syncthreads();

    // ---- Phase C: attention, kt-outer, P fully in registers (zero-shuffle PV).
    // k-slot permutation: slot 8q+j <-> token nk0+4q+j (j<4), nk0+16+4q+(j-4) (j>=4);
    // applied identically to pa and vb so the PV product is unchanged.
    bf16x8 qa[2];
#pragma unroll
    for (int qt = 0; qt < 2; ++qt)
        qa[qt] = *(const bf16x8*)&qn[w * 32 + qt * 16 + l15][quad * 8];

    const f32x4 zf = {0.f, 0.f, 0.f, 0.f};
    f32x4 o[2][2];
#pragma unroll
    for (int qt = 0; qt < 2; ++qt) { o[qt][0] = zf; o[qt][1] = zf; }
    float dsm[2] = {0.f, 0.f};

    // preload kt=0 K/V frags
    bf16x8 kb0 = *(const bf16x8*)&kn[l15][quad * 8];
    bf16x8 kb1 = *(const bf16x8*)&kn[16 + l15][quad * 8];
    bf16x4 vp0 = *(const bf16x4*)&vT[l15][quad * 4];
    bf16x4 vp1 = *(const bf16x4*)&vT[l15][16 + quad * 4];
    bf16x4 vp2 = *(const bf16x4*)&vT[16 + l15][quad * 4];
    bf16x4 vp3 = *(const bf16x4*)&vT[16 + l15][16 + quad * 4];

#pragma unroll
    for (int kt = 0; kt < 8; ++kt) {  // 32 keys per chunk
        // all 4 S-MFMAs up front -> 16 independent exps below
        f32x4 s00 = MFMA16(kb0, qa[0], zf);
        f32x4 s01 = MFMA16(kb1, qa[0], zf);
        f32x4 s10 = MFMA16(kb0, qa[1], zf);
        f32x4 s11 = MFMA16(kb1, qa[1], zf);
        bf16x8 vb0 = pack2(vp0, vp1);
        bf16x8 vb1 = pack2(vp2, vp3);
        if (kt < 7) {  // next kt's K/V LDS reads, issued before the exp block
            int nk = kt * 32 + 32;
            kb0 = *(const bf16x8*)&kn[nk + l15][quad * 8];
            kb1 = *(const bf16x8*)&kn[nk + 16 + l15][quad * 8];
            vp0 = *(const bf16x4*)&vT[l15][nk + quad * 4];
            vp1 = *(const bf16x4*)&vT[l15][nk + 16 + quad * 4];
            vp2 = *(const bf16x4*)&vT[16 + l15][nk + quad * 4];
            vp3 = *(const bf16x4*)&vT[16 + l15][nk + 16 + quad * 4];
        }
        bf16x8 pa0, pa1;
        float d0 = 0.f, d1 = 0.f;
#pragma unroll
        for (int r = 0; r < 4; ++r) {
            float p00 = __builtin_amdgcn_exp2f(s00[r]);
            float p01 = __builtin_amdgcn_exp2f(s01[r]);
            float p10 = __builtin_amdgcn_exp2f(s10[r]);
            float p11 = __builtin_amdgcn_exp2f(s11[r]);
            d0 += p00 + p01;  d1 += p10 + p11;
            pa0[r] = (bf16)p00; pa0[4 + r] = (bf16)p01;  // pairs -> v_cvt_pk_bf16_f32
            pa1[r] = (bf16)p10; pa1[4 + r] = (bf16)p11;
        }
        dsm[0] += d0;  dsm[1] += d1;
        o[0][0] = MFMA16(pa0, vb0, o[0][0]);
        o[0][1] = MFMA16(pa0, vb1, o[0][1]);
        o[1][0] = MFMA16(pa1, vb0, o[1][0]);
        o[1][1] = MFMA16(pa1, vb1, o[1][1]);
    }

    // denom: reduce per-lane partials over the 4 quads -> full denom per query
#pragma unroll
    for (int qt = 0; qt < 2; ++qt) {
        dsm[qt] += __shfl_xor(dsm[qt], 16);
        dsm[qt] += __shfl_xor(dsm[qt], 32);
    }
    bf16* opbase = attn_out + (size_t)(b * NT + w * 32) * DIM + h * HD;
#pragma unroll
    for (int qt = 0; qt < 2; ++qt)
#pragma unroll
        for (int r = 0; r < 4; ++r) {
            // O row = query quad*4+r; its denom lives at lane l15 == quad*4+r
            float inv = 1.f / __shfl(dsm[qt], quad * 4 + r);
            int nq = qt * 16 + quad * 4 + r;
            opbase[(size_t)nq * DIM + l15]      = (bf16)(o[qt][0][r] * inv);
            opbase[(size_t)nq * DIM + 16 + l15] = (bf16)(o[qt][1][r] * inv);
        }
}

// ---------------- K3: proj GEMM (96-ch tiles, K-split LDS weights) ----------------
__launch_bounds__(256, 2)
__global__ void k_proj(const bf16* __restrict__ xa, const bf16* __restrict__ wp,
                       const float* __restrict__ proj_b, float* __restrict__ out) {
    __shared__ __align__(16) bf16 wsm[96][200];   // half tile 96x192 (pad 200), 38.4KB
    __shared__ float bias_s[96];
    // XCD-pinned decode (grid = 1024): 4 cb-slices of a batch share one L2.
    const int n_ = blockIdx.x;
    const int xcd = n_ & 7;
    const int ww = n_ >> 3;               // 0..127
    const int b  = xcd * 32 + (ww >> 2);
    const int cb = ww & 3;                // 96-wide slice of 384 out channels

    const int tid = threadIdx.x;
    const int lane = tid & 63, w = tid >> 6;
    const int l15 = lane & 15, quad = lane >> 4;
    if (tid < 96) bias_s[tid] = proj_b[cb * 96 + tid];

    auto stage_w = [&](int hk) {
#pragma unroll
        for (int i = 0; i < 9; ++i) {
            int c = tid + i * 256;        // 2304 chunks = 96 rows x 24
            int row = c / 24, ch = c % 24;
            *(bf16x8*)&wsm[row][ch * 8] =
                *(const bf16x8*)(wp + (size_t)(cb * 96 + row) * DIM + hk * 192 + ch * 8);
        }
    };
    stage_w(0);
    __syncthreads();

    f32x4 acc[6][4];
#pragma unroll
    for (int jt = 0; jt < 6; ++jt)
#pragma unroll
        for (int tt = 0; tt < 4; ++tt) acc[jt][tt] = (f32x4){0.f, 0.f, 0.f, 0.f};

    const bf16* brow[4];
#pragma unroll
    for (int tt = 0; tt < 4; ++tt)
        brow[tt] = xa + (size_t)(b * NT + w * 64 + tt * 16 + l15) * DIM + quad * 8;

    // one-ahead dbuf on xa B-frags; A-frags from LDS per kc
    bf16x8 bfr[2][4];
#pragma unroll
    for (int tt = 0; tt < 4; ++tt) bfr[0][tt] = *(const bf16x8*)(brow[tt]);

#pragma unroll 1
    for (int hk = 0; hk < 2; ++hk) {
        if (hk) {
            __syncthreads();
            stage_w(1);
            __syncthreads();
        }
#pragma unroll
        for (int kc6 = 0; kc6 < 6; ++kc6) {
            const int kc = hk * 6 + kc6;
            const int cur = kc & 1, nxt = cur ^ 1;
            if (kc < 11) {
                int k0 = (kc + 1) * 32;
#pragma unroll
                for (int tt = 0; tt < 4; ++tt) bfr[nxt][tt] = *(const bf16x8*)(brow[tt] + k0);
            }
            bf16x8 afr[6];
#pragma unroll
            for (int jt = 0; jt < 6; ++jt)
                afr[jt] = *(const bf16x8*)&wsm[jt * 16 + l15][kc6 * 32 + quad * 8];
#pragma unroll
            for (int jt = 0; jt < 6; ++jt)
#pragma unroll
                for (int tt = 0; tt < 4; ++tt)
                    acc[jt][tt] = MFMA16(afr[jt], bfr[cur][tt], acc[jt][tt]);
        }
    }

    float* op = out + (size_t)b * DIM * NT;  // out[b][c][n]
#pragma unroll
    for (int jt = 0; jt < 6; ++jt)
#pragma unroll
        for (int tt = 0; tt < 4; ++tt)
#pragma unroll
            for (int r = 0; r < 4; ++r) {
                int cl = jt * 16 + quad * 4 + r;          // D row = out channel (local)
                int n  = w * 64 + tt * 16 + l15;          // D col = token
                op[(size_t)(cb * 96 + cl) * NT + n] = acc[jt][tt][r] + bias_s[cl];
            }
}

extern "C" void kernel_launch(void* const* d_in, const int* in_sizes, int n_in,
                              void* d_out, int out_size, void* d_ws, size_t ws_size,
                              hipStream_t stream) {
    const float* x      = (const float*)d_in[0];
    const float* qkv_w  = (const float*)d_in[1];
    const float* qkv_b  = (const float*)d_in[2];
    const float* proj_w = (const float*)d_in[3];
    const float* proj_b = (const float*)d_in[4];
    float* out = (float*)d_out;

    char* ws = (char*)d_ws;
    bf16* xt = (bf16*)ws;                    // 256*256*384*2 = 50,331,648 B
    bf16* xa = (bf16*)(ws + 50331648);       // 50,331,648 B
    bf16* wq = (bf16*)(ws + 100663296);      // 884,736 B
    bf16* wp = (bf16*)(ws + 101548032);      // 294,912 B  (total 101,842,944 B)

    k_cast_w<<<dim3(1728), dim3(256), 0, stream>>>(qkv_w, proj_w, wq, wp);
    k_transpose_cast<<<dim3(8, 12, 256), dim3(32, 8), 0, stream>>>(x, xt);
    k_qkv_attn<<<dim3(NH * 256), dim3(512), 0, stream>>>(xt, wq, qkv_b, xa);
    k_proj<<<dim3(4 * 256), dim3(256), 0, stream>>>(xa, wp, proj_b, out);
}